// Round 1
// 73.578 us; speedup vs baseline: 1.1859x; 1.1859x over previous
//
#include <hip/hip_runtime.h>

// LaneATT greedy line-NMS, v2: one-shot top-K candidate selection.
//
// v1 (87.3 us measured) rescanned all 8192 keys per pop with 2 block
// barriers per iteration. Profile shows the timed region is dominated by
// 2x 256MiB harness poison-fills (~80us @ 6.7TB/s); the kernel slice is
// ~7us. v2 attacks that slice:
//
//  * Provable pruning: T = 16th largest of the 64 group-maxima (groups of
//    4 threads / 128 keys). >=16 groups have max >= T => >=16 keys >= T
//    => T <= K16, so {keys >= T} is a superset of the global top-16.
//    Expected candidate count ~18 for iid scores.
//  * Gather candidates with one LDS atomic counter, bitonic-sort up to 64
//    of them across wave 0's lanes (in-register, ~21 shfl stages).
//  * Bulk-prefetch all candidate rows into LDS once (16x78 floats), then
//    run the entire pop loop wave-synchronous on wave 0: no block
//    barriers, __ballot for the suppress decision, 8 lanes per kept row
//    for the strip-distance sum (was a 72-iter serial loop).
//  * Unconditional correctness: overflow (>64 candidates) or list
//    exhaustion before topk falls back to the original pipelined
//    scan-per-pop loop, resuming strictly below the last popped key.
//
// 256 threads (4 waves) on one CU.

#define NTH     256
#define SLOTS   32           // NTH*SLOTS = 8192 >= n
#define NWAVES  (NTH / 64)
#define N_OFF   72
#define NSTRIP  71
#define PROW    77
#define MAXK    8
#define CANDMAX 64           // candidate-list capacity (= one wave)
#define PRE     16           // rows prefetched into LDS up front

__device__ __forceinline__ unsigned long long pack_key(float s, int idx) {
    return ((unsigned long long)__float_as_uint(s) << 32) |
           (unsigned long long)(0xFFFFFFFFu - (unsigned)idx);
}
__device__ __forceinline__ int key_idx(unsigned long long k) {
    return (int)(0xFFFFFFFFu - (unsigned)(k & 0xFFFFFFFFu));
}

// Descending bitonic sort of one u64 per lane across a 64-lane wave.
__device__ __forceinline__ unsigned long long bitonic64_desc(
        unsigned long long v, int lane) {
#pragma unroll
    for (int k = 2; k <= 64; k <<= 1) {
#pragma unroll
        for (int j = k >> 1; j > 0; j >>= 1) {
            unsigned long long pv = __shfl_xor(v, j);
            bool lower   = (lane & j) == 0;
            bool dirdesc = (lane & k) != 0;
            bool keepmax = (dirdesc != lower);      // global descending
            unsigned long long mx = v > pv ? v : pv;
            unsigned long long mn = v > pv ? pv : v;
            v = keepmax ? mx : mn;
        }
    }
    return v;
}

__global__ __launch_bounds__(NTH, 1) void lane_nms(
    const float* __restrict__ prop,
    const float* __restrict__ scores,
    const int* __restrict__ p_thres,
    const int* __restrict__ p_topk,
    float* __restrict__ out,
    int n, int out_rows)
{
    const int tid  = threadIdx.x;
    const int lane = tid & 63;
    const int wv   = tid >> 6;

    __shared__ unsigned long long s_wmax[NWAVES];
    __shared__ unsigned long long s_tmax[NTH];
    __shared__ unsigned long long s_cand[CANDMAX];
    __shared__ unsigned long long s_thr64;
    __shared__ unsigned long long s_resume;
    __shared__ float s_rows[PRE][PROW + 1];       // candidate rows + score
    __shared__ float s_buf[2][PROW + 1];          // fallback double-buffer
    __shared__ float s_kxs[MAXK][N_OFF];          // kept rows' xs
    __shared__ int   s_ks[MAXK], s_ke[MAXK];
    __shared__ int   s_sup[2];
    __shared__ int   s_cnt, s_kept, s_fb;

    const float thr = (float)(*p_thres);
    int topk = *p_topk;
    if (topk > out_rows) topk = out_rows;
    if (topk > MAXK)     topk = MAXK;

    // ---- build keys (32/thread, float4 score loads) + per-thread max ----
    unsigned long long key[SLOTS];
#pragma unroll
    for (int jo = 0; jo < SLOTS / 4; ++jo) {
        int base = jo * (NTH * 4) + tid * 4;
        if (base + 3 < n) {
            const float4 s4 = *reinterpret_cast<const float4*>(scores + base);
            key[jo * 4 + 0] = pack_key(s4.x, base + 0);
            key[jo * 4 + 1] = pack_key(s4.y, base + 1);
            key[jo * 4 + 2] = pack_key(s4.z, base + 2);
            key[jo * 4 + 3] = pack_key(s4.w, base + 3);
        } else {
#pragma unroll
            for (int c = 0; c < 4; ++c) {
                int idx = base + c;
                key[jo * 4 + c] = (idx < n) ? pack_key(scores[idx], idx) : 0ULL;
            }
        }
    }
    unsigned long long tmax = 0ULL;
#pragma unroll
    for (int j = 0; j < SLOTS; ++j)
        if (key[j] > tmax) tmax = key[j];

    s_tmax[tid] = tmax;
    if (tid == 0) { s_cnt = 0; s_sup[0] = 0; s_sup[1] = 0; }
    __syncthreads();

    // ---- wave0: T = 16th largest of 64 group-maxima (provably <= K16) ----
    if (wv == 0) {
        unsigned long long g = s_tmax[lane * 4 + 0];
        unsigned long long t1 = s_tmax[lane * 4 + 1]; if (t1 > g) g = t1;
        unsigned long long t2 = s_tmax[lane * 4 + 2]; if (t2 > g) g = t2;
        unsigned long long t3 = s_tmax[lane * 4 + 3]; if (t3 > g) g = t3;
        g = bitonic64_desc(g, lane);
        if (lane == 15) s_thr64 = g;
    }
    __syncthreads();
    const unsigned long long T = s_thr64;

    // ---- gather all keys >= T (superset of global top-16) ----
#pragma unroll
    for (int j = 0; j < SLOTS; ++j) {
        unsigned long long k = key[j];
        if (k != 0ULL && k >= T) {
            int pos = atomicAdd(&s_cnt, 1);
            if (pos < CANDMAX) s_cand[pos] = k;
        }
    }
    __syncthreads();
    const int  cnt  = s_cnt;
    const bool fast = (cnt <= CANDMAX) && (topk > 0);

    int kept = 0;
    bool fb = (topk > 0);
    unsigned long long resume = ~0ULL;

    if (fast) {
        const int ncand = cnt;
        // sort candidates descending (wave 0, in-register)
        if (wv == 0) {
            unsigned long long v = (lane < ncand) ? s_cand[lane] : 0ULL;
            v = bitonic64_desc(v, lane);
            s_cand[lane] = v;
        }
        __syncthreads();

        // bulk-prefetch first npre candidate rows: one latency hit total
        const int npre = ncand < PRE ? ncand : PRE;
        for (int i = tid; i < npre * (PROW + 1); i += NTH) {
            int r = i / (PROW + 1), c = i - r * (PROW + 1);
            int w = key_idx(s_cand[r]);
            s_rows[r][c] = (c < PROW) ? prop[(size_t)w * PROW + c] : scores[w];
        }
        __syncthreads();

        // ---- pop loop: wave 0 only, wave-synchronous, zero block barriers
        if (wv == 0) {
            int  pref = npre;
            int  k0 = 0;
            bool hit_topk = false;
            for (int c = 0; c < ncand; ++c) {
                if (c >= pref) {               // on-demand row (rare, c>=16)
                    int w = key_idx(s_cand[c]);
                    for (int i = lane; i < PROW + 1; i += 64)
                        s_rows[c & (PRE - 1)][i] =
                            (i < PROW) ? prop[(size_t)w * PROW + i] : scores[w];
                    asm volatile("s_waitcnt lgkmcnt(0)" ::: "memory");
                    pref = c + 1;
                }
                const int slot = c & (PRE - 1);
                float sy = s_rows[slot][2];
                float ln = s_rows[slot][4];
                int cs = (int)rintf(sy * (float)NSTRIP);   // half-even == jnp.round
                int ce = cs + (int)rintf(ln) - 1;
                if (ce > NSTRIP) ce = NSTRIP;

                // 8 lanes per kept row: strip sums in parallel
                bool pred = false;
                {
                    int j = lane >> 3, l = lane & 7;
                    if (j < k0) {
                        int ps = cs > s_ks[j] ? cs : s_ks[j];
                        int pe = ce < s_ke[j] ? ce : s_ke[j];
                        if (pe >= ps) {
                            float d = 0.0f;
                            for (int k = ps + l; k <= pe; k += 8)
                                d += fabsf(s_rows[slot][5 + k] - s_kxs[j][k]);
                            d += __shfl_down(d, 4, 8);
                            d += __shfl_down(d, 2, 8);
                            d += __shfl_down(d, 1, 8);
                            if (l == 0 && d / (float)(pe - ps + 1) < thr)
                                pred = true;
                        }
                    }
                }
                if (__ballot((int)pred) == 0ULL) {         // keep: uniform
                    for (int i = lane; i < PROW + 1; i += 64)
                        out[k0 * (PROW + 1) + i] = s_rows[slot][i];
                    for (int i = lane; i < N_OFF; i += 64)
                        s_kxs[k0][i] = s_rows[slot][5 + i];
                    if (lane == 0) { s_ks[k0] = cs; s_ke[k0] = ce; }
                    ++k0;
                    if (k0 >= topk) { hit_topk = true; break; }
                    asm volatile("s_waitcnt lgkmcnt(0)" ::: "memory");
                }
            }
            if (lane == 0) {
                s_kept   = k0;
                s_fb     = (!hit_topk && k0 < topk) ? 1 : 0;
                s_resume = (ncand > 0) ? s_cand[ncand - 1] : 0ULL;
            }
        }
        __syncthreads();
        kept   = s_kept;
        fb     = (s_fb != 0);
        resume = s_resume;
    }

    // ---- fallback: original pipelined lazy loop (overflow / exhaustion) ----
    if (fb && kept < topk) {
        auto scan = [&](unsigned long long lim) {
            unsigned long long m = 0ULL;
#pragma unroll
            for (int j = 0; j < SLOTS; ++j) {
                unsigned long long k = key[j];
                if (k < lim && k > m) m = k;
            }
#pragma unroll
            for (int off = 32; off > 0; off >>= 1) {
                unsigned long long o = __shfl_down(m, off);
                if (o > m) m = o;
            }
            if (lane == 0) s_wmax[wv] = m;
        };
        auto merge = [&]() {
            unsigned long long m = s_wmax[0];
#pragma unroll
            for (int i = 1; i < NWAVES; ++i)
                if (s_wmax[i] > m) m = s_wmax[i];
            return m;
        };

        scan(resume);
        __syncthreads();
        unsigned long long k1 = merge();
        __syncthreads();
        scan(k1);
        __syncthreads();
        unsigned long long k2 = merge();

        if (k1 != 0ULL) {
            int w = key_idx(k1);
            if (tid < PROW)       s_buf[0][tid]  = prop[(size_t)w * PROW + tid];
            else if (tid == PROW) s_buf[0][PROW] = scores[w];
        }
        if (k2 != 0ULL) {
            int w = key_idx(k2);
            if (tid >= NTH - PROW - 1) {
                int t = tid - (NTH - PROW - 1);
                s_buf[1][t] = (t < PROW) ? prop[(size_t)w * PROW + t] : scores[w];
            }
        }
        __syncthreads();

        int p = 0, q = 0;
        unsigned long long curk = k1, nxtk = k2;
        while (curk != 0ULL) {
            scan(nxtk);
            float sy = s_buf[p][2];
            float ln = s_buf[p][4];
            int cs = (int)rintf(sy * (float)NSTRIP);
            int ce = cs + (int)rintf(ln) - 1;
            if (ce > NSTRIP) ce = NSTRIP;
            if (tid < kept) {
                int ps = cs > s_ks[tid] ? cs : s_ks[tid];
                int pe = ce < s_ke[tid] ? ce : s_ke[tid];
                if (pe >= ps) {
                    float d = 0.0f;
                    for (int k = ps; k <= pe; ++k)
                        d += fabsf(s_buf[p][5 + k] - s_kxs[tid][k]);
                    if (d / (float)(pe - ps + 1) < thr) s_sup[q] = 1;
                }
            }
            if (tid == NTH - 1) s_sup[q ^ 1] = 0;
            __syncthreads();                           // A

            unsigned long long k3 = merge();
            if (s_sup[q] == 0) {
                if (tid < PROW + 1) out[kept * (PROW + 1) + tid] = s_buf[p][tid];
                if (tid < N_OFF)    s_kxs[kept][tid] = s_buf[p][5 + tid];
                if (tid == 0) { s_ks[kept] = cs; s_ke[kept] = ce; }
                ++kept;
                if (kept >= topk) break;
            }
            __syncthreads();                           // B

            if (k3 != 0ULL) {
                int w = key_idx(k3);
                if (tid < PROW)       s_buf[p][tid]  = prop[(size_t)w * PROW + tid];
                else if (tid == PROW) s_buf[p][PROW] = scores[w];
            }
            curk = nxtk; nxtk = k3; p ^= 1; q ^= 1;
        }
    }

    // ---- epilogue: zero unused rows (d_out poisoned 0xAA), write count ----
    for (int i = tid; i < (out_rows - kept) * (PROW + 1); i += NTH)
        out[kept * (PROW + 1) + i] = 0.0f;
    if (tid == 0) out[out_rows * (PROW + 1)] = (float)kept;
}

extern "C" void kernel_launch(void* const* d_in, const int* in_sizes, int n_in,
                              void* d_out, int out_size, void* d_ws, size_t ws_size,
                              hipStream_t stream) {
    const float* prop   = (const float*)d_in[0];
    const float* scores = (const float*)d_in[1];
    const int*   thres  = (const int*)d_in[2];
    const int*   topk   = (const int*)d_in[3];
    int n        = in_sizes[1];
    int out_rows = (out_size - 1) / (PROW + 1);   // 624/78 = 8
    lane_nms<<<1, NTH, 0, stream>>>(prop, scores, thres, topk,
                                    (float*)d_out, n, out_rows);
}

// Round 2
// 70.849 us; speedup vs baseline: 1.2316x; 1.0385x over previous
//
#include <hip/hip_runtime.h>

// LaneATT greedy line-NMS, v3: parallel pairwise suppression matrix.
//
// v1 (87.3us): per-pop full rescan + serial 72-strip classify, 2 block
//   barriers/pop.  v2 (73.6us): one-shot top-16 candidate selection +
//   wave-synchronous pop loop.  Profile: timed region is dominated by the
//   harness's 256MiB poison-fills (~40us each @ 83% HBM peak = fill
//   roofline); the kernel slice is now a few us, of which the ~9-iteration
//   sequential pop loop (~350-450cy dependent chain per pop) is the
//   largest removable piece.
//
// v3: the sorted candidates ARE the global top-16 (16th-group-max
// threshold guarantee), so compute greedy NMS reference-style:
//  * one parallel 16x16 pairwise pass (256 threads = 1 pair/thread,
//    exec-masked strip loop) -> per-candidate suppress bitmask,
//  * ~16-step serial greedy over bitmasks on thread 0 (~100cy),
//  * parallel write-out of kept rows.
// Greedy equivalence: when i is popped all j<i are decided; reference's
// late re-marking of already-kept rows is a no-op; so removed|=mask[i]
// over j>i reproduces jax.lax.scan exactly.
//
// Unconditional correctness: candidate overflow (>64) or <topk kept among
// the top-16 falls back to the v1 pipelined scan-per-pop loop, resuming
// strictly below s_cand[15].
//
// 256 threads (4 waves) on one CU.

#define NTH     256
#define SLOTS   32           // NTH*SLOTS = 8192 >= n
#define NWAVES  (NTH / 64)
#define N_OFF   72
#define NSTRIP  71
#define PROW    77
#define MAXK    8
#define CANDMAX 64           // candidate-list capacity (= one wave)
#define PRE     16           // rows prefetched into LDS / matrix size

__device__ __forceinline__ unsigned long long pack_key(float s, int idx) {
    return ((unsigned long long)__float_as_uint(s) << 32) |
           (unsigned long long)(0xFFFFFFFFu - (unsigned)idx);
}
__device__ __forceinline__ int key_idx(unsigned long long k) {
    return (int)(0xFFFFFFFFu - (unsigned)(k & 0xFFFFFFFFu));
}

// Descending bitonic sort of one u64 per lane across a 64-lane wave.
__device__ __forceinline__ unsigned long long bitonic64_desc(
        unsigned long long v, int lane) {
#pragma unroll
    for (int k = 2; k <= 64; k <<= 1) {
#pragma unroll
        for (int j = k >> 1; j > 0; j >>= 1) {
            unsigned long long pv = __shfl_xor(v, j);
            bool lower   = (lane & j) == 0;
            bool dirdesc = (lane & k) != 0;
            bool keepmax = (dirdesc != lower);      // global descending
            unsigned long long mx = v > pv ? v : pv;
            unsigned long long mn = v > pv ? pv : v;
            v = keepmax ? mx : mn;
        }
    }
    return v;
}

__global__ __launch_bounds__(NTH, 1) void lane_nms(
    const float* __restrict__ prop,
    const float* __restrict__ scores,
    const int* __restrict__ p_thres,
    const int* __restrict__ p_topk,
    float* __restrict__ out,
    int n, int out_rows)
{
    const int tid  = threadIdx.x;
    const int lane = tid & 63;
    const int wv   = tid >> 6;

    __shared__ unsigned long long s_wmax[NWAVES];
    __shared__ unsigned long long s_tmax[NTH];
    __shared__ unsigned long long s_cand[CANDMAX];
    __shared__ unsigned long long s_thr64;
    __shared__ unsigned long long s_resume;
    __shared__ float s_rows[PRE][PROW + 1];       // candidate rows + score
    __shared__ float s_buf[2][PROW + 1];          // fallback double-buffer
    __shared__ float s_kxs[MAXK][N_OFF];          // kept rows' xs (fallback)
    __shared__ int   s_ks[MAXK], s_ke[MAXK];
    __shared__ int   s_sup[2];
    __shared__ unsigned int s_sup32[PRE];         // i -> bitmask of j it kills
    __shared__ int   s_keptidx[MAXK];
    __shared__ int   s_cnt, s_kept, s_fb;

    const float thr = (float)(*p_thres);
    int topk = *p_topk;
    if (topk > out_rows) topk = out_rows;
    if (topk > MAXK)     topk = MAXK;

    // ---- build keys (32/thread, float4 score loads) + per-thread max ----
    unsigned long long key[SLOTS];
#pragma unroll
    for (int jo = 0; jo < SLOTS / 4; ++jo) {
        int base = jo * (NTH * 4) + tid * 4;
        if (base + 3 < n) {
            const float4 s4 = *reinterpret_cast<const float4*>(scores + base);
            key[jo * 4 + 0] = pack_key(s4.x, base + 0);
            key[jo * 4 + 1] = pack_key(s4.y, base + 1);
            key[jo * 4 + 2] = pack_key(s4.z, base + 2);
            key[jo * 4 + 3] = pack_key(s4.w, base + 3);
        } else {
#pragma unroll
            for (int c = 0; c < 4; ++c) {
                int idx = base + c;
                key[jo * 4 + c] = (idx < n) ? pack_key(scores[idx], idx) : 0ULL;
            }
        }
    }
    unsigned long long tmax = 0ULL;
#pragma unroll
    for (int j = 0; j < SLOTS; ++j)
        if (key[j] > tmax) tmax = key[j];

    s_tmax[tid] = tmax;
    if (tid == 0) { s_cnt = 0; s_sup[0] = 0; s_sup[1] = 0; }
    __syncthreads();

    // ---- wave0: T = 16th largest of 64 group-maxima (provably <= K16) ----
    if (wv == 0) {
        unsigned long long g = s_tmax[lane * 4 + 0];
        unsigned long long t1 = s_tmax[lane * 4 + 1]; if (t1 > g) g = t1;
        unsigned long long t2 = s_tmax[lane * 4 + 2]; if (t2 > g) g = t2;
        unsigned long long t3 = s_tmax[lane * 4 + 3]; if (t3 > g) g = t3;
        g = bitonic64_desc(g, lane);
        if (lane == 15) s_thr64 = g;
    }
    __syncthreads();
    const unsigned long long T = s_thr64;

    // ---- gather all keys >= T (superset of global top-16) ----
#pragma unroll
    for (int j = 0; j < SLOTS; ++j) {
        unsigned long long k = key[j];
        if (k != 0ULL && k >= T) {
            int pos = atomicAdd(&s_cnt, 1);
            if (pos < CANDMAX) s_cand[pos] = k;
        }
    }
    __syncthreads();
    const int  cnt  = s_cnt;
    const bool fast = (cnt <= CANDMAX) && (topk > 0);

    int kept = 0;
    bool fb = (topk > 0);
    unsigned long long resume = ~0ULL;

    if (fast) {
        const int ncand = cnt;
        // sort candidates descending (wave 0, in-register)
        if (wv == 0) {
            unsigned long long v = (lane < ncand) ? s_cand[lane] : 0ULL;
            v = bitonic64_desc(v, lane);
            s_cand[lane] = v;
        }
        __syncthreads();

        // bulk-prefetch first npre candidate rows; init suppress masks
        const int npre = ncand < PRE ? ncand : PRE;
        if (tid < PRE) s_sup32[tid] = 0u;
        for (int i = tid; i < npre * (PROW + 1); i += NTH) {
            int r = i / (PROW + 1), c = i - r * (PROW + 1);
            int w = key_idx(s_cand[r]);
            s_rows[r][c] = (c < PROW) ? prop[(size_t)w * PROW + c] : scores[w];
        }
        __syncthreads();

        // ---- pairwise suppression matrix: thread (i,j), i<j: does i kill j?
        {
            int i = tid >> 4, j = tid & 15;
            if (i < j && j < npre) {
                float syi = s_rows[i][2], lni = s_rows[i][4];
                int csi = (int)rintf(syi * (float)NSTRIP);   // half-even
                int cei = csi + (int)rintf(lni) - 1;
                if (cei > NSTRIP) cei = NSTRIP;
                float syj = s_rows[j][2], lnj = s_rows[j][4];
                int csj = (int)rintf(syj * (float)NSTRIP);
                int cej = csj + (int)rintf(lnj) - 1;
                if (cej > NSTRIP) cej = NSTRIP;
                int ps = csi > csj ? csi : csj;
                int pe = cei < cej ? cei : cej;
                if (pe >= ps) {
                    float d = 0.0f;
                    for (int k = ps; k <= pe; ++k)
                        d += fabsf(s_rows[i][5 + k] - s_rows[j][5 + k]);
                    if (d / (float)(pe - ps + 1) < thr)
                        atomicOr(&s_sup32[i], 1u << j);
                }
            }
        }
        __syncthreads();

        // ---- serial greedy over 16 bitmasks (thread 0, ~100cy) ----
        if (tid == 0) {
            unsigned removed = 0u;
            int k0 = 0;
            for (int i = 0; i < npre && k0 < topk; ++i) {
                if (!((removed >> i) & 1u)) {
                    s_keptidx[k0++] = i;
                    removed |= s_sup32[i];
                }
            }
            s_kept   = k0;
            s_fb     = (k0 < topk) ? 1 : 0;
            s_resume = (npre > 0) ? s_cand[npre - 1] : 0ULL;
        }
        __syncthreads();
        kept   = s_kept;
        fb     = (s_fb != 0);
        resume = s_resume;

        // ---- parallel write-out of kept rows ----
        for (int i = tid; i < kept * (PROW + 1); i += NTH) {
            int kk = i / (PROW + 1), c = i - kk * (PROW + 1);
            out[i] = s_rows[s_keptidx[kk]][c];
        }
        if (fb) {
            // fallback needs kept-row state in s_kxs/s_ks/s_ke
            for (int i = tid; i < kept * N_OFF; i += NTH) {
                int kk = i / N_OFF, c = i - kk * N_OFF;
                s_kxs[kk][c] = s_rows[s_keptidx[kk]][5 + c];
            }
            if (tid < kept) {
                int slot = s_keptidx[tid];
                float sy = s_rows[slot][2], ln = s_rows[slot][4];
                int cs = (int)rintf(sy * (float)NSTRIP);
                int ce = cs + (int)rintf(ln) - 1;
                if (ce > NSTRIP) ce = NSTRIP;
                s_ks[tid] = cs; s_ke[tid] = ce;
            }
            // ordering vs fallback classify is covered by the fallback
            // prologue's own __syncthreads.
        }
    }

    // ---- fallback: original pipelined lazy loop (overflow / exhaustion) ----
    if (fb && kept < topk) {
        auto scan = [&](unsigned long long lim) {
            unsigned long long m = 0ULL;
#pragma unroll
            for (int j = 0; j < SLOTS; ++j) {
                unsigned long long k = key[j];
                if (k < lim && k > m) m = k;
            }
#pragma unroll
            for (int off = 32; off > 0; off >>= 1) {
                unsigned long long o = __shfl_down(m, off);
                if (o > m) m = o;
            }
            if (lane == 0) s_wmax[wv] = m;
        };
        auto merge = [&]() {
            unsigned long long m = s_wmax[0];
#pragma unroll
            for (int i = 1; i < NWAVES; ++i)
                if (s_wmax[i] > m) m = s_wmax[i];
            return m;
        };

        scan(resume);
        __syncthreads();
        unsigned long long k1 = merge();
        __syncthreads();
        scan(k1);
        __syncthreads();
        unsigned long long k2 = merge();

        if (k1 != 0ULL) {
            int w = key_idx(k1);
            if (tid < PROW)       s_buf[0][tid]  = prop[(size_t)w * PROW + tid];
            else if (tid == PROW) s_buf[0][PROW] = scores[w];
        }
        if (k2 != 0ULL) {
            int w = key_idx(k2);
            if (tid >= NTH - PROW - 1) {
                int t = tid - (NTH - PROW - 1);
                s_buf[1][t] = (t < PROW) ? prop[(size_t)w * PROW + t] : scores[w];
            }
        }
        __syncthreads();

        int p = 0, q = 0;
        unsigned long long curk = k1, nxtk = k2;
        while (curk != 0ULL) {
            scan(nxtk);
            float sy = s_buf[p][2];
            float ln = s_buf[p][4];
            int cs = (int)rintf(sy * (float)NSTRIP);
            int ce = cs + (int)rintf(ln) - 1;
            if (ce > NSTRIP) ce = NSTRIP;
            if (tid < kept) {
                int ps = cs > s_ks[tid] ? cs : s_ks[tid];
                int pe = ce < s_ke[tid] ? ce : s_ke[tid];
                if (pe >= ps) {
                    float d = 0.0f;
                    for (int k = ps; k <= pe; ++k)
                        d += fabsf(s_buf[p][5 + k] - s_kxs[tid][k]);
                    if (d / (float)(pe - ps + 1) < thr) s_sup[q] = 1;
                }
            }
            if (tid == NTH - 1) s_sup[q ^ 1] = 0;
            __syncthreads();                           // A

            unsigned long long k3 = merge();
            if (s_sup[q] == 0) {
                if (tid < PROW + 1) out[kept * (PROW + 1) + tid] = s_buf[p][tid];
                if (tid < N_OFF)    s_kxs[kept][tid] = s_buf[p][5 + tid];
                if (tid == 0) { s_ks[kept] = cs; s_ke[kept] = ce; }
                ++kept;
                if (kept >= topk) break;
            }
            __syncthreads();                           // B

            if (k3 != 0ULL) {
                int w = key_idx(k3);
                if (tid < PROW)       s_buf[p][tid]  = prop[(size_t)w * PROW + tid];
                else if (tid == PROW) s_buf[p][PROW] = scores[w];
            }
            curk = nxtk; nxtk = k3; p ^= 1; q ^= 1;
        }
    }

    // ---- epilogue: zero unused rows (d_out poisoned 0xAA), write count ----
    for (int i = tid; i < (out_rows - kept) * (PROW + 1); i += NTH)
        out[kept * (PROW + 1) + i] = 0.0f;
    if (tid == 0) out[out_rows * (PROW + 1)] = (float)kept;
}

extern "C" void kernel_launch(void* const* d_in, const int* in_sizes, int n_in,
                              void* d_out, int out_size, void* d_ws, size_t ws_size,
                              hipStream_t stream) {
    const float* prop   = (const float*)d_in[0];
    const float* scores = (const float*)d_in[1];
    const int*   thres  = (const int*)d_in[2];
    const int*   topk   = (const int*)d_in[3];
    int n        = in_sizes[1];
    int out_rows = (out_size - 1) / (PROW + 1);   // 624/78 = 8
    lane_nms<<<1, NTH, 0, stream>>>(prop, scores, thres, topk,
                                    (float*)d_out, n, out_rows);
}